// Round 2
// baseline (680.912 us; speedup 1.0000x reference)
//
#include <hip/hip_runtime.h>
#include <hip/hip_bf16.h>

// Problem dims (fixed by the reference)
#define M_DIM 8192   // B_*S = 4*2048
#define N_DIM 4096   // D_OUT
#define K_DIM 4096   // D_IN
#define R_DIM 64

typedef __attribute__((ext_vector_type(8))) short bf16x8;
typedef __attribute__((ext_vector_type(4))) float f32x4;

// round-to-nearest-even fp32 -> bf16 (inputs are finite; no NaN handling needed)
__device__ __forceinline__ ushort f2bf(float f) {
  union { float f; unsigned u; } v; v.f = f;
  unsigned r = v.u + 0x7fffu + ((v.u >> 16) & 1u);
  return (ushort)(r >> 16);
}

__device__ __forceinline__ void gload16(const void* g, void* l) {
  __builtin_amdgcn_global_load_lds(
      (const __attribute__((address_space(1))) void*)g,
      (__attribute__((address_space(3))) void*)l, 16, 0, 0);
}

// ---------------------------------------------------------------------------
// Kernel 1: x (fp32) -> bf16, vectorized float4 -> ushort4
// ---------------------------------------------------------------------------
__global__ void cvt_x_bf16(const float* __restrict__ x, ushort* __restrict__ xb, int n4) {
  int i = blockIdx.x * blockDim.x + threadIdx.x;
  int stride = gridDim.x * blockDim.x;
  const float4* x4 = (const float4*)x;
  ushort4* o4 = (ushort4*)xb;
  for (; i < n4; i += stride) {
    float4 v = x4[i];
    ushort4 o;
    o.x = f2bf(v.x); o.y = f2bf(v.y); o.z = f2bf(v.z); o.w = f2bf(v.w);
    o4[i] = o;
  }
}

// ---------------------------------------------------------------------------
// Kernel 2: W_comb[o][i] = bf16( W_base[o][i] + 0.25 * sum_r (B+WR)[o][r]*(A+WL)[r][i] )
// grid = 64 o-blocks x 8 i-strips = 512 blocks, 256 threads.
// Each block: 64 o-rows; stages (B+WR) tile once, loops 8 chunks of 64 cols.
// ---------------------------------------------------------------------------
__global__ void wcomb_bf16(const float* __restrict__ Wb, const float* __restrict__ lB,
                           const float* __restrict__ lWR, const float* __restrict__ lA,
                           const float* __restrict__ lWL, ushort* __restrict__ Wc) {
  __shared__ float BcT[64][65];  // [r][o_local], padded (+1) against write conflicts
  __shared__ float Ac[64][64];   // [r][i_local]
  const int t = threadIdx.x;
  const int ob = blockIdx.x >> 3;
  const int strip = blockIdx.x & 7;
  const int o0 = ob * 64;

  // stage BcT: global read coalesced over r, LDS write stride 65 (conflict-free)
#pragma unroll
  for (int e = 0; e < 16; ++e) {
    int idx = t + e * 256;
    int r = idx & 63, ol = idx >> 6;
    BcT[r][ol] = lB[(o0 + ol) * 64 + r] + lWR[(o0 + ol) * 64 + r];
  }

  const int to = (t & 15) * 4;
  const int ti = (t >> 4) * 4;

  for (int ic = 0; ic < 8; ++ic) {
    const int i0 = strip * 512 + ic * 64;
    __syncthreads();  // Bc visible (iter 0); previous compute done before Ac overwrite
#pragma unroll
    for (int e = 0; e < 16; ++e) {
      int idx = t + e * 256;
      int il = idx & 63, r = idx >> 6;
      Ac[r][il] = lA[r * 4096 + i0 + il] + lWL[r * 4096 + i0 + il];
    }
    __syncthreads();

    float acc[4][4] = {};
#pragma unroll 8
    for (int r = 0; r < 64; ++r) {
      float b0 = BcT[r][to], b1 = BcT[r][to + 1], b2 = BcT[r][to + 2], b3 = BcT[r][to + 3];
      float4 a4 = *(const float4*)&Ac[r][ti];
      acc[0][0] = fmaf(b0, a4.x, acc[0][0]); acc[0][1] = fmaf(b0, a4.y, acc[0][1]);
      acc[0][2] = fmaf(b0, a4.z, acc[0][2]); acc[0][3] = fmaf(b0, a4.w, acc[0][3]);
      acc[1][0] = fmaf(b1, a4.x, acc[1][0]); acc[1][1] = fmaf(b1, a4.y, acc[1][1]);
      acc[1][2] = fmaf(b1, a4.z, acc[1][2]); acc[1][3] = fmaf(b1, a4.w, acc[1][3]);
      acc[2][0] = fmaf(b2, a4.x, acc[2][0]); acc[2][1] = fmaf(b2, a4.y, acc[2][1]);
      acc[2][2] = fmaf(b2, a4.z, acc[2][2]); acc[2][3] = fmaf(b2, a4.w, acc[2][3]);
      acc[3][0] = fmaf(b3, a4.x, acc[3][0]); acc[3][1] = fmaf(b3, a4.y, acc[3][1]);
      acc[3][2] = fmaf(b3, a4.z, acc[3][2]); acc[3][3] = fmaf(b3, a4.w, acc[3][3]);
    }

#pragma unroll
    for (int oo = 0; oo < 4; ++oo) {
      size_t base = (size_t)(o0 + to + oo) * 4096 + i0 + ti;
      float4 wv = *(const float4*)&Wb[base];
      ushort4 ov;
      ov.x = f2bf(wv.x + 0.25f * acc[oo][0]);
      ov.y = f2bf(wv.y + 0.25f * acc[oo][1]);
      ov.z = f2bf(wv.z + 0.25f * acc[oo][2]);
      ov.w = f2bf(wv.w + 0.25f * acc[oo][3]);
      *(ushort4*)&Wc[base] = ov;
    }
  }
}

// ---------------------------------------------------------------------------
// Kernel 3: out[m][n] = sum_k Xb[m][k]*Wc[n][k] + bias[n]   (B^T GEMM, m97 structure)
// 128x128 tile, BK=32, 4 waves (2x2) of 64x64, mfma_f32_16x16x32_bf16, 4x4 frags.
// ---------------------------------------------------------------------------
__global__ __launch_bounds__(256) void gemm_bt(const ushort* __restrict__ Xb,
                                               const ushort* __restrict__ Wc,
                                               const float* __restrict__ bias,
                                               float* __restrict__ out) {
  __shared__ ushort As[128 * 32];
  __shared__ ushort Bs[128 * 32];
  const int t = threadIdx.x;
  const int lane = t & 63;
  const int w = t >> 6;
  const int wr = w >> 1, wc = w & 1;
  const int bn = blockIdx.x & 31;  // 32 N tiles
  const int bm = blockIdx.x >> 5;  // 64 M tiles
  const int m0 = bm * 128, n0 = bn * 128;
  const int ln15 = lane & 15, k8 = (lane >> 4) * 8;

  // staging: 512 16B segments per tile; thread t owns segs t and t+256.
  // LDS dest for seg s is byte s*16 (lane-linear per wave: base w*1024 + lane*16).
  const int srow = t >> 2, scol = (t & 3) * 8;
  const ushort* gA0 = Xb + (size_t)(m0 + srow) * K_DIM + scol;
  const ushort* gA1 = Xb + (size_t)(m0 + 64 + srow) * K_DIM + scol;
  const ushort* gB0 = Wc + (size_t)(n0 + srow) * K_DIM + scol;
  const ushort* gB1 = Wc + (size_t)(n0 + 64 + srow) * K_DIM + scol;

  f32x4 zero = {0.0f, 0.0f, 0.0f, 0.0f};
  f32x4 acc[4][4];
#pragma unroll
  for (int i = 0; i < 4; ++i)
#pragma unroll
    for (int j = 0; j < 4; ++j) acc[i][j] = zero;

  for (int kt = 0; kt < K_DIM / 32; ++kt) {
    const int kofs = kt * 32;
    gload16(gA0 + kofs, &As[t * 8]);
    gload16(gA1 + kofs, &As[2048 + t * 8]);
    gload16(gB0 + kofs, &Bs[t * 8]);
    gload16(gB1 + kofs, &Bs[2048 + t * 8]);
    __syncthreads();  // drains vmcnt -> tiles resident

    bf16x8 af[4], bfr[4];
#pragma unroll
    for (int f = 0; f < 4; ++f) {
      af[f] = *(const bf16x8*)&As[(wr * 64 + f * 16 + ln15) * 32 + k8];
      bfr[f] = *(const bf16x8*)&Bs[(wc * 64 + f * 16 + ln15) * 32 + k8];
    }
#pragma unroll
    for (int mf = 0; mf < 4; ++mf)
#pragma unroll
      for (int nf = 0; nf < 4; ++nf)
        acc[mf][nf] = __builtin_amdgcn_mfma_f32_16x16x32_bf16(af[mf], bfr[nf], acc[mf][nf], 0, 0, 0);
    __syncthreads();  // reads done before next stage overwrites
  }

  // epilogue: C/D layout col=lane&15, row=(lane>>4)*4+reg  [m89/m91 verified]
  const int rb = m0 + wr * 64 + (lane >> 4) * 4;
  const int cb = n0 + wc * 64 + ln15;
#pragma unroll
  for (int nf = 0; nf < 4; ++nf) {
    int col = cb + nf * 16;
    float bb = bias[col];
#pragma unroll
    for (int mf = 0; mf < 4; ++mf) {
#pragma unroll
      for (int j = 0; j < 4; ++j) {
        out[(size_t)(rb + mf * 16 + j) * N_DIM + col] = acc[mf][nf][j] + bb;
      }
    }
  }
}

// ---------------------------------------------------------------------------
extern "C" void kernel_launch(void* const* d_in, const int* in_sizes, int n_in,
                              void* d_out, int out_size, void* d_ws, size_t ws_size,
                              hipStream_t stream) {
  const float* x   = (const float*)d_in[0];
  const float* Wb  = (const float*)d_in[1];
  const float* bb  = (const float*)d_in[2];
  const float* lA  = (const float*)d_in[3];
  const float* lB  = (const float*)d_in[4];
  const float* lWL = (const float*)d_in[5];
  const float* lWR = (const float*)d_in[6];
  float* out = (float*)d_out;

  // ws layout: Xb (bf16, 8192x4096 = 64 MB) | Wc (bf16, 4096x4096 = 32 MB)
  ushort* Xb = (ushort*)d_ws;
  ushort* Wc = (ushort*)((char*)d_ws + (size_t)M_DIM * K_DIM * 2);

  cvt_x_bf16<<<2048, 256, 0, stream>>>(x, Xb, M_DIM * K_DIM / 4);
  wcomb_bf16<<<512, 256, 0, stream>>>(Wb, lB, lWR, lA, lWL, Wc);
  gemm_bt<<<dim3(64 * 32), 256, 0, stream>>>(Xb, Wc, bb, out);
}

// Round 5
// 606.165 us; speedup vs baseline: 1.1233x; 1.1233x over previous
//
#include <hip/hip_runtime.h>
#include <hip/hip_bf16.h>

// Problem dims (fixed by the reference)
#define M_DIM 8192   // B_*S
#define N_DIM 4096   // D_OUT
#define K_DIM 4096   // D_IN

typedef __attribute__((ext_vector_type(8))) short bf16x8;
typedef __attribute__((ext_vector_type(4))) float f32x4;

// round-to-nearest-even fp32 -> bf16
__device__ __forceinline__ ushort f2bf(float f) {
  union { float f; unsigned u; } v; v.f = f;
  unsigned r = v.u + 0x7fffu + ((v.u >> 16) & 1u);
  return (ushort)(r >> 16);
}

__device__ __forceinline__ void gload16(const void* g, void* l) {
  __builtin_amdgcn_global_load_lds(
      (const __attribute__((address_space(1))) void*)g,
      (__attribute__((address_space(3))) void*)l, 16, 0, 0);
}

// ---------------------------------------------------------------------------
// Fused prep: blocks [0,2048) convert x fp32->bf16; blocks [2048,2560) build
// Wc = bf16(W_base + 0.25*(B+WR)(A+WL)).  Independent work -> overlaps on GPU.
// ---------------------------------------------------------------------------
__global__ void prep(const float* __restrict__ x, ushort* __restrict__ xb,
                     const float* __restrict__ Wb, const float* __restrict__ lB,
                     const float* __restrict__ lWR, const float* __restrict__ lA,
                     const float* __restrict__ lWL, ushort* __restrict__ Wc) {
  __shared__ float BcT[64][65];
  __shared__ float Ac[64][64];
  const int t = threadIdx.x;

  if (blockIdx.x < 2048) {
    // ---- cvt part: x (fp32) -> bf16, float4 -> ushort4 ----
    int i = blockIdx.x * 256 + t;
    const int n4 = M_DIM * K_DIM / 4;
    const float4* x4 = (const float4*)x;
    ushort4* o4 = (ushort4*)xb;
    for (; i < n4; i += 2048 * 256) {
      float4 v = x4[i];
      ushort4 o;
      o.x = f2bf(v.x); o.y = f2bf(v.y); o.z = f2bf(v.z); o.w = f2bf(v.w);
      o4[i] = o;
    }
    return;
  }

  // ---- wcomb part: 512 blocks ----
  const int bid = blockIdx.x - 2048;
  const int ob = bid >> 3;
  const int strip = bid & 7;
  const int o0 = ob * 64;

#pragma unroll
  for (int e = 0; e < 16; ++e) {
    int idx = t + e * 256;
    int r = idx & 63, ol = idx >> 6;
    BcT[r][ol] = lB[(o0 + ol) * 64 + r] + lWR[(o0 + ol) * 64 + r];
  }

  const int to = (t & 15) * 4;
  const int ti = (t >> 4) * 4;

  for (int ic = 0; ic < 8; ++ic) {
    const int i0 = strip * 512 + ic * 64;
    __syncthreads();
#pragma unroll
    for (int e = 0; e < 16; ++e) {
      int idx = t + e * 256;
      int il = idx & 63, r = idx >> 6;
      Ac[r][il] = lA[r * 4096 + i0 + il] + lWL[r * 4096 + i0 + il];
    }
    __syncthreads();

    float acc[4][4] = {};
#pragma unroll 8
    for (int r = 0; r < 64; ++r) {
      float b0 = BcT[r][to], b1 = BcT[r][to + 1], b2 = BcT[r][to + 2], b3 = BcT[r][to + 3];
      float4 a4 = *(const float4*)&Ac[r][ti];
      acc[0][0] = fmaf(b0, a4.x, acc[0][0]); acc[0][1] = fmaf(b0, a4.y, acc[0][1]);
      acc[0][2] = fmaf(b0, a4.z, acc[0][2]); acc[0][3] = fmaf(b0, a4.w, acc[0][3]);
      acc[1][0] = fmaf(b1, a4.x, acc[1][0]); acc[1][1] = fmaf(b1, a4.y, acc[1][1]);
      acc[1][2] = fmaf(b1, a4.z, acc[1][2]); acc[1][3] = fmaf(b1, a4.w, acc[1][3]);
      acc[2][0] = fmaf(b2, a4.x, acc[2][0]); acc[2][1] = fmaf(b2, a4.y, acc[2][1]);
      acc[2][2] = fmaf(b2, a4.z, acc[2][2]); acc[2][3] = fmaf(b2, a4.w, acc[2][3]);
      acc[3][0] = fmaf(b3, a4.x, acc[3][0]); acc[3][1] = fmaf(b3, a4.y, acc[3][1]);
      acc[3][2] = fmaf(b3, a4.z, acc[3][2]); acc[3][3] = fmaf(b3, a4.w, acc[3][3]);
    }

#pragma unroll
    for (int oo = 0; oo < 4; ++oo) {
      size_t base = (size_t)(o0 + to + oo) * 4096 + i0 + ti;
      float4 wv = *(const float4*)&Wb[base];
      ushort4 ov;
      ov.x = f2bf(wv.x + 0.25f * acc[oo][0]);
      ov.y = f2bf(wv.y + 0.25f * acc[oo][1]);
      ov.z = f2bf(wv.z + 0.25f * acc[oo][2]);
      ov.w = f2bf(wv.w + 0.25f * acc[oo][3]);
      *(ushort4*)&Wc[base] = ov;
    }
  }
}

// ---------------------------------------------------------------------------
// GEMM: out[m][n] = sum_k Xb[m][k]*Wc[n][k] + bias[n]
// 256x256 tile, BK=32, ring-of-4 LDS buffers (128 KiB), 8 waves (2Mx4N),
// per-wave 128x64 (acc 8x4 of 16x16), counted vmcnt(8) pipeline (T4),
// T2 XOR-swizzle on LDS, T5 setprio around MFMA, T1 XCD swizzle.
//
// Safety argument (per-wave FIFO vmcnt): at iter kt, after issuing stage(kt+3),
// outstanding loads = shares of {kt+1, kt+2, kt+3}. vmcnt(8) retires all but
// the newest 8 (= kt+2, kt+3) -> kt+1 fully landed before the barrier into
// iter kt+1. Stage(kt+3) writes buf[(kt+3)&3] = buf[(kt-1)&3], whose readers
// all finished before the barrier that ended iter kt-1 (ds_read data was
// consumed into VGPRs before the MFMAs that precede that barrier).
// ---------------------------------------------------------------------------
__global__ __launch_bounds__(512, 2) void gemm256(const ushort* __restrict__ Xb,
                                                  const ushort* __restrict__ Wc,
                                                  const float* __restrict__ bias,
                                                  float* __restrict__ out) {
  __shared__ char smem[131072];  // 4 bufs x (A 16K | B 16K)
  const int t = threadIdx.x;
  const int lane = t & 63;
  const int wid = t >> 6;
  const int wm = wid >> 2, wn = wid & 3;
  const int ln15 = lane & 15;
  const int hi16 = (lane >> 4) * 16;

  // T1: XCD-aware swizzle; 512 wgs, 64 per XCD (512 % 8 == 0 -> bijective)
  const int swz = (blockIdx.x & 7) * 64 + (blockIdx.x >> 3);
  const int bm = swz >> 4, bn = swz & 15;
  const int m0 = bm * 256, n0 = bn * 256;

  // ---- swizzled ds_read byte offsets (T2: byte ^= ((byte>>7)&3)<<4) ----
  int offA[8], offB[4];
  {
    const int rbA = wm * 128 + ln15;
    const int xa = ((rbA >> 1) & 3) << 4;   // bits 7-8 of row*64 depend only on row>>1
#pragma unroll
    for (int mf = 0; mf < 8; ++mf) offA[mf] = ((rbA + mf * 16) * 64 + hi16) ^ xa;
    const int rbB = wn * 64 + ln15;
    const int xb2 = ((rbB >> 1) & 3) << 4;
#pragma unroll
    for (int nf = 0; nf < 4; ++nf) offB[nf] = ((rbB + nf * 16) * 64 + hi16) ^ xb2;
  }

  // ---- staging: dest linear (gload_lds requirement), source pre-swizzled ----
  const int d0 = t * 16, d1 = 8192 + t * 16;
  const int s0 = d0 ^ (((d0 >> 7) & 3) << 4);
  const int s1 = d1 ^ (((d1 >> 7) & 3) << 4);
  const ushort* pA0 = Xb + (size_t)(m0 + (s0 >> 6)) * K_DIM + ((s0 & 63) >> 1);
  const ushort* pA1 = Xb + (size_t)(m0 + (s1 >> 6)) * K_DIM + ((s1 & 63) >> 1);
  const ushort* pB0 = Wc + (size_t)(n0 + (s0 >> 6)) * K_DIM + ((s0 & 63) >> 1);
  const ushort* pB1 = Wc + (size_t)(n0 + (s1 >> 6)) * K_DIM + ((s1 & 63) >> 1);

  f32x4 acc[8][4];
  f32x4 zero = {0.f, 0.f, 0.f, 0.f};
#pragma unroll
  for (int i = 0; i < 8; ++i)
#pragma unroll
    for (int j = 0; j < 4; ++j) acc[i][j] = zero;

#define STAGE(kt, c)                                         \
  do {                                                       \
    char* sb_ = smem + (c) * 32768;                          \
    gload16(pA0 + (kt) * 32, sb_ + d0);                      \
    gload16(pA1 + (kt) * 32, sb_ + d1);                      \
    gload16(pB0 + (kt) * 32, sb_ + 16384 + d0);              \
    gload16(pB1 + (kt) * 32, sb_ + 16384 + d1);              \
  } while (0)

  // prologue: tiles 0,1,2 in flight; wait tile0 (newest 8 = tiles 1,2 in flight)
  STAGE(0, 0); STAGE(1, 1); STAGE(2, 2);
  asm volatile("s_waitcnt vmcnt(8)" ::: "memory");
  __builtin_amdgcn_s_barrier();
  __builtin_amdgcn_sched_barrier(0);

#define ITER(kt, c)                                                             \
  do {                                                                          \
    if ((kt) + 3 < 128) STAGE((kt) + 3, ((c) + 3) & 3);                         \
    const char* sA = smem + (c) * 32768;                                        \
    const char* sB = sA + 16384;                                                \
    bf16x8 af[8], bg[4];                                                        \
    _Pragma("unroll") for (int mf = 0; mf < 8; ++mf)                            \
        af[mf] = *(const bf16x8*)(sA + offA[mf]);                               \
    _Pragma("unroll") for (int nf = 0; nf < 4; ++nf)                            \
        bg[nf] = *(const bf16x8*)(sB + offB[nf]);                               \
    __builtin_amdgcn_s_setprio(1);                                              \
    _Pragma("unroll") for (int mf = 0; mf < 8; ++mf)                            \
      _Pragma("unroll") for (int nf = 0; nf < 4; ++nf)                          \
        acc[mf][nf] = __builtin_amdgcn_mfma_f32_16x16x32_bf16(                  \
            af[mf], bg[nf], acc[mf][nf], 0, 0, 0);                              \
    __builtin_amdgcn_s_setprio(0);                                              \
    if ((kt) < 125) { asm volatile("s_waitcnt vmcnt(8)" ::: "memory"); }        \
    else            { asm volatile("s_waitcnt vmcnt(0)" ::: "memory"); }        \
    __builtin_amdgcn_s_barrier();                                               \
    __builtin_amdgcn_sched_barrier(0);                                          \
  } while (0)

  for (int ktb = 0; ktb < 128; ktb += 4) {
    ITER(ktb + 0, 0);
    ITER(ktb + 1, 1);
    ITER(ktb + 2, 2);
    ITER(ktb + 3, 3);
  }
#undef ITER
#undef STAGE

  // epilogue: C/D layout col=lane&15, row=(lane>>4)*4+reg  [m89/m91 verified]
  const int rb = m0 + wm * 128 + (lane >> 4) * 4;
  const int cb = n0 + wn * 64 + ln15;
#pragma unroll
  for (int nf = 0; nf < 4; ++nf) {
    const int col = cb + nf * 16;
    const float bbv = bias[col];
#pragma unroll
    for (int mf = 0; mf < 8; ++mf) {
#pragma unroll
      for (int j = 0; j < 4; ++j) {
        out[(size_t)(rb + mf * 16 + j) * N_DIM + col] = acc[mf][nf][j] + bbv;
      }
    }
  }
}

// ---------------------------------------------------------------------------
extern "C" void kernel_launch(void* const* d_in, const int* in_sizes, int n_in,
                              void* d_out, int out_size, void* d_ws, size_t ws_size,
                              hipStream_t stream) {
  const float* x   = (const float*)d_in[0];
  const float* Wb  = (const float*)d_in[1];
  const float* bb  = (const float*)d_in[2];
  const float* lA  = (const float*)d_in[3];
  const float* lB  = (const float*)d_in[4];
  const float* lWL = (const float*)d_in[5];
  const float* lWR = (const float*)d_in[6];
  float* out = (float*)d_out;

  ushort* Xb = (ushort*)d_ws;
  ushort* Wc = (ushort*)((char*)d_ws + (size_t)M_DIM * K_DIM * 2);

  prep<<<2560, 256, 0, stream>>>(x, Xb, Wb, lB, lWR, lA, lWL, Wc);
  gemm256<<<512, 512, 0, stream>>>(Xb, Wc, bb, out);
}